// Round 2
// baseline (2374.399 us; speedup 1.0000x reference)
//
#include <hip/hip_runtime.h>
#include <hip/hip_bf16.h>

#define N_NODES 100000
#define N_EDGES 3200000
#define F_IN    512
#define H_DIM   64
#define C_DIM   64
#define K_STEPS 10
#define ALPHA   0.1f

// ---- bf16 helpers (storage only; all math fp32) ----
__device__ __forceinline__ float bf2f(ushort u) {
    union { unsigned int i; float f; } c; c.i = ((unsigned int)u) << 16; return c.f;
}
__device__ __forceinline__ ushort f2bf(float f) {
    union { float f; unsigned int i; } c; c.f = f;
    unsigned int lsb = (c.i >> 16) & 1u;
    unsigned int r = c.i + 0x7fffu + lsb;   // round to nearest even
    return (ushort)(r >> 16);
}

// ---------------------------------------------------------------- zero
__global__ void zero_kernel(int* __restrict__ deg, int* __restrict__ cursor, int n) {
    int i = blockIdx.x * blockDim.x + threadIdx.x;
    if (i < n) { deg[i] = 0; cursor[i] = 0; }
}

// ---------------------------------------------------------------- degree (in-degree by dst)
__global__ void deg_kernel(const int* __restrict__ dst, int* __restrict__ deg, int e) {
    int i = blockIdx.x * blockDim.x + threadIdx.x;
    if (i < e) atomicAdd(&deg[dst[i]], 1);
}

// ---------------------------------------------------------------- dinv / self weight
__global__ void dinv_kernel(const int* __restrict__ deg, float* __restrict__ dinv,
                            float* __restrict__ selfw, int n) {
    int i = blockIdx.x * blockDim.x + threadIdx.x;
    if (i < n) {
        float dg = (float)deg[i] + 1.0f;
        float di = rsqrtf(dg);
        dinv[i]  = di;
        selfw[i] = di * di;
    }
}

// ---------------------------------------------------------------- exclusive scan (single block, 1024 thr)
__global__ void scan_kernel(const int* __restrict__ deg, int* __restrict__ row_start, int n) {
    __shared__ int wsum[16];
    __shared__ int carry_s;
    int tid = threadIdx.x;
    int lane = tid & 63;
    int w = tid >> 6;
    if (tid == 0) carry_s = 0;
    __syncthreads();
    for (int base = 0; base < n; base += 1024) {
        int i = base + tid;
        int v = (i < n) ? deg[i] : 0;
        int incl = v;
        #pragma unroll
        for (int off = 1; off < 64; off <<= 1) {
            int t = __shfl_up(incl, off);
            if (lane >= off) incl += t;
        }
        if (lane == 63) wsum[w] = incl;
        __syncthreads();
        int woff = 0;
        #pragma unroll
        for (int j = 0; j < 16; ++j) woff += (j < w) ? wsum[j] : 0;
        int carry = carry_s;
        if (i < n) row_start[i] = carry + woff + (incl - v);
        __syncthreads();
        if (tid == 0) {
            int tot = 0;
            #pragma unroll
            for (int j = 0; j < 16; ++j) tot += wsum[j];
            carry_s += tot;
        }
        __syncthreads();
    }
    if (threadIdx.x == 0) row_start[n] = carry_s;
}

// ---------------------------------------------------------------- CSR scatter
__global__ void scatter_kernel(const int* __restrict__ src, const int* __restrict__ dst,
                               const int* __restrict__ row_start, int* __restrict__ cursor,
                               const float* __restrict__ dinv, int* __restrict__ csr_src,
                               float* __restrict__ csr_norm, int e) {
    int i = blockIdx.x * blockDim.x + threadIdx.x;
    if (i >= e) return;
    int s = src[i], d = dst[i];
    int pos = row_start[d] + atomicAdd(&cursor[d], 1);
    csr_src[pos]  = s;
    csr_norm[pos] = dinv[s] * dinv[d];
}

// ---------------------------------------------------------------- fused MLP: h = relu(x@W1^T+b1)@W2^T+b2  (bf16 out)
// 1 row/thread, W1 read from global (L1/L2-served, wave-uniform), W2 in LDS.
__global__ __launch_bounds__(256) void mlp_kernel(
    const float* __restrict__ x, const float* __restrict__ W1, const float* __restrict__ b1,
    const float* __restrict__ W2, const float* __restrict__ b2, ushort* __restrict__ h, int n)
{
    __shared__ float w2s[64 * 64];
    __shared__ float b2s[64];
    for (int i = threadIdx.x; i < 64 * 64; i += 256) w2s[i] = W2[i];
    if (threadIdx.x < 64) b2s[threadIdx.x] = b2[threadIdx.x];
    __syncthreads();

    int r = blockIdx.x * 256 + threadIdx.x;
    if (r >= n) return;

    float acc[64];
    #pragma unroll
    for (int o = 0; o < 64; ++o) acc[o] = b1[o];

    const float* xr = x + (size_t)r * F_IN;
    for (int k = 0; k < F_IN; k += 4) {
        float4 xv = *reinterpret_cast<const float4*>(xr + k);
        #pragma unroll
        for (int o = 0; o < 64; ++o) {
            const float4 wv = *reinterpret_cast<const float4*>(&W1[o * F_IN + k]);
            acc[o] = fmaf(xv.x, wv.x, acc[o]);
            acc[o] = fmaf(xv.y, wv.y, acc[o]);
            acc[o] = fmaf(xv.z, wv.z, acc[o]);
            acc[o] = fmaf(xv.w, wv.w, acc[o]);
        }
    }
    #pragma unroll
    for (int o = 0; o < 64; ++o) acc[o] = fmaxf(acc[o], 0.f);

    ushort* hr = h + (size_t)r * C_DIM;
    #pragma unroll
    for (int c0 = 0; c0 < 64; c0 += 8) {
        float s[8];
        #pragma unroll
        for (int j = 0; j < 8; ++j) s[j] = b2s[c0 + j];
        #pragma unroll
        for (int o = 0; o < 64; ++o) {
            float a = acc[o];
            #pragma unroll
            for (int j = 0; j < 8; ++j) s[j] = fmaf(a, w2s[(c0 + j) * 64 + o], s[j]);
        }
        union { ushort u[8]; uint4 v; } pk;
        #pragma unroll
        for (int j = 0; j < 8; ++j) pk.u[j] = f2bf(s[j]);
        *reinterpret_cast<uint4*>(hr + c0) = pk.v;
    }
}

// ---------------------------------------------------------------- one APPNP step: wave per node, lane = channel (bf16 z)
__global__ __launch_bounds__(256) void appnp_kernel(
    const int* __restrict__ row_start, const int* __restrict__ csr_src,
    const float* __restrict__ csr_norm, const float* __restrict__ selfw,
    const ushort* __restrict__ zin, const ushort* __restrict__ h,
    ushort* __restrict__ zout, int n)
{
    int idx = blockIdx.x * blockDim.x + threadIdx.x;
    int wid = idx >> 6;
    int lane = idx & 63;
    if (wid >= n) return;
    int beg = row_start[wid];
    int end = row_start[wid + 1];
    float a0 = 0.f, a1 = 0.f, a2 = 0.f, a3 = 0.f;
    int e = beg;
    for (; e + 3 < end; e += 4) {
        int s0 = csr_src[e], s1 = csr_src[e + 1], s2 = csr_src[e + 2], s3 = csr_src[e + 3];
        float w0 = csr_norm[e], w1 = csr_norm[e + 1], w2 = csr_norm[e + 2], w3 = csr_norm[e + 3];
        a0 = fmaf(w0, bf2f(zin[(size_t)s0 * 64 + lane]), a0);
        a1 = fmaf(w1, bf2f(zin[(size_t)s1 * 64 + lane]), a1);
        a2 = fmaf(w2, bf2f(zin[(size_t)s2 * 64 + lane]), a2);
        a3 = fmaf(w3, bf2f(zin[(size_t)s3 * 64 + lane]), a3);
    }
    for (; e < end; ++e) {
        int s = csr_src[e];
        a0 = fmaf(csr_norm[e], bf2f(zin[(size_t)s * 64 + lane]), a0);
    }
    float acc = (a0 + a1) + (a2 + a3);
    float zi = bf2f(zin[(size_t)wid * 64 + lane]);
    float agg = acc + selfw[wid] * zi;
    float res = (1.0f - ALPHA) * agg + ALPHA * bf2f(h[(size_t)wid * 64 + lane]);
    zout[(size_t)wid * 64 + lane] = f2bf(res);
}

// ---------------------------------------------------------------- log_softmax over C=64 (wave per node)
__global__ __launch_bounds__(256) void logsoftmax_kernel(const ushort* __restrict__ z,
                                                         float* __restrict__ out, int n) {
    int idx = blockIdx.x * blockDim.x + threadIdx.x;
    int wid = idx >> 6;
    int lane = idx & 63;
    if (wid >= n) return;
    float v = bf2f(z[(size_t)wid * 64 + lane]);
    float m = v;
    #pragma unroll
    for (int off = 32; off > 0; off >>= 1) m = fmaxf(m, __shfl_xor(m, off));
    float ex = expf(v - m);
    float s = ex;
    #pragma unroll
    for (int off = 32; off > 0; off >>= 1) s += __shfl_xor(s, off);
    out[(size_t)wid * 64 + lane] = v - m - logf(s);
}

// ---------------------------------------------------------------- launch
extern "C" void kernel_launch(void* const* d_in, const int* in_sizes, int n_in,
                              void* d_out, int out_size, void* d_ws, size_t ws_size,
                              hipStream_t stream) {
    const float* x  = (const float*)d_in[0];
    const float* W1 = (const float*)d_in[1];
    const float* b1 = (const float*)d_in[2];
    const float* W2 = (const float*)d_in[3];
    const float* b2 = (const float*)d_in[4];
    const int*   ei = (const int*)d_in[5];
    const int* src = ei;
    const int* dst = ei + N_EDGES;
    float* out = (float*)d_out;

    char* ws = (char*)d_ws;
    size_t off = 0;
    auto alloc = [&](size_t bytes) -> void* {
        void* p = ws + off;
        off += (bytes + 255) & ~(size_t)255;
        return p;
    };
    int*    deg       = (int*)   alloc((size_t)N_NODES * 4);
    int*    cursor    = (int*)   alloc((size_t)N_NODES * 4);
    int*    row_start = (int*)   alloc((size_t)(N_NODES + 1) * 4);
    float*  dinv      = (float*) alloc((size_t)N_NODES * 4);
    float*  selfw     = (float*) alloc((size_t)N_NODES * 4);
    int*    csr_src   = (int*)   alloc((size_t)N_EDGES * 4);
    float*  csr_norm  = (float*) alloc((size_t)N_EDGES * 4);
    ushort* h         = (ushort*)alloc((size_t)N_NODES * C_DIM * 2);
    ushort* za        = (ushort*)alloc((size_t)N_NODES * C_DIM * 2);
    ushort* zb        = (ushort*)alloc((size_t)N_NODES * C_DIM * 2);

    zero_kernel<<<(N_NODES + 255) / 256, 256, 0, stream>>>(deg, cursor, N_NODES);
    deg_kernel<<<(N_EDGES + 255) / 256, 256, 0, stream>>>(dst, deg, N_EDGES);
    dinv_kernel<<<(N_NODES + 255) / 256, 256, 0, stream>>>(deg, dinv, selfw, N_NODES);
    scan_kernel<<<1, 1024, 0, stream>>>(deg, row_start, N_NODES);
    scatter_kernel<<<(N_EDGES + 255) / 256, 256, 0, stream>>>(src, dst, row_start, cursor,
                                                              dinv, csr_src, csr_norm, N_EDGES);
    mlp_kernel<<<(N_NODES + 255) / 256, 256, 0, stream>>>(x, W1, b1, W2, b2, h, N_NODES);

    const ushort* zin = h;
    ushort* zout = za;
    for (int k = 0; k < K_STEPS; ++k) {
        appnp_kernel<<<(N_NODES * 64 + 255) / 256, 256, 0, stream>>>(
            row_start, csr_src, csr_norm, selfw, zin, h, zout, N_NODES);
        zin = zout;
        zout = (zout == za) ? zb : za;
    }
    logsoftmax_kernel<<<(N_NODES * 64 + 255) / 256, 256, 0, stream>>>(zin, out, N_NODES);
}

// Round 3
// 1617.629 us; speedup vs baseline: 1.4678x; 1.4678x over previous
//
#include <hip/hip_runtime.h>
#include <hip/hip_bf16.h>

#define N_NODES 100000
#define N_EDGES 3200000
#define F_IN    512
#define H_DIM   64
#define C_DIM   64
#define K_STEPS 10
#define ALPHA   0.1f

typedef __attribute__((ext_vector_type(8))) short bf16x8;
typedef __attribute__((ext_vector_type(4))) float f32x4;

// ---- bf16 helpers (storage only; all math fp32) ----
__device__ __forceinline__ float bf2f(ushort u) {
    union { unsigned int i; float f; } c; c.i = ((unsigned int)u) << 16; return c.f;
}
__device__ __forceinline__ ushort f2bf(float f) {
    union { float f; unsigned int i; } c; c.f = f;
    unsigned int lsb = (c.i >> 16) & 1u;
    unsigned int r = c.i + 0x7fffu + lsb;   // round to nearest even
    return (ushort)(r >> 16);
}

// ---------------------------------------------------------------- zero
__global__ void zero_kernel(int* __restrict__ deg, int* __restrict__ cursor, int n) {
    int i = blockIdx.x * blockDim.x + threadIdx.x;
    if (i < n) { deg[i] = 0; cursor[i] = 0; }
}

// ---------------------------------------------------------------- degree (in-degree by dst)
__global__ void deg_kernel(const int* __restrict__ dst, int* __restrict__ deg, int e) {
    int i = blockIdx.x * blockDim.x + threadIdx.x;
    if (i < e) atomicAdd(&deg[dst[i]], 1);
}

// ---------------------------------------------------------------- dinv / self weight
__global__ void dinv_kernel(const int* __restrict__ deg, float* __restrict__ dinv,
                            float* __restrict__ selfw, int n) {
    int i = blockIdx.x * blockDim.x + threadIdx.x;
    if (i < n) {
        float dg = (float)deg[i] + 1.0f;
        float di = rsqrtf(dg);
        dinv[i]  = di;
        selfw[i] = di * di;
    }
}

// ---------------------------------------------------------------- exclusive scan (single block, 1024 thr)
__global__ void scan_kernel(const int* __restrict__ deg, int* __restrict__ row_start, int n) {
    __shared__ int wsum[16];
    __shared__ int carry_s;
    int tid = threadIdx.x;
    int lane = tid & 63;
    int w = tid >> 6;
    if (tid == 0) carry_s = 0;
    __syncthreads();
    for (int base = 0; base < n; base += 1024) {
        int i = base + tid;
        int v = (i < n) ? deg[i] : 0;
        int incl = v;
        #pragma unroll
        for (int off = 1; off < 64; off <<= 1) {
            int t = __shfl_up(incl, off);
            if (lane >= off) incl += t;
        }
        if (lane == 63) wsum[w] = incl;
        __syncthreads();
        int woff = 0;
        #pragma unroll
        for (int j = 0; j < 16; ++j) woff += (j < w) ? wsum[j] : 0;
        int carry = carry_s;
        if (i < n) row_start[i] = carry + woff + (incl - v);
        __syncthreads();
        if (tid == 0) {
            int tot = 0;
            #pragma unroll
            for (int j = 0; j < 16; ++j) tot += wsum[j];
            carry_s += tot;
        }
        __syncthreads();
    }
    if (threadIdx.x == 0) row_start[n] = carry_s;
}

// ---------------------------------------------------------------- CSR scatter
__global__ void scatter_kernel(const int* __restrict__ src, const int* __restrict__ dst,
                               const int* __restrict__ row_start, int* __restrict__ cursor,
                               const float* __restrict__ dinv, int* __restrict__ csr_src,
                               float* __restrict__ csr_norm, int e) {
    int i = blockIdx.x * blockDim.x + threadIdx.x;
    if (i >= e) return;
    int s = src[i], d = dst[i];
    int pos = row_start[d] + atomicAdd(&cursor[d], 1);
    csr_src[pos]  = s;
    csr_norm[pos] = dinv[s] * dinv[d];
}

// ---------------------------------------------------------------- convert weights to bf16
__global__ void cvt_w_kernel(const float* __restrict__ W1, const float* __restrict__ W2,
                             ushort* __restrict__ w1bf, ushort* __restrict__ w2bf) {
    int i = blockIdx.x * blockDim.x + threadIdx.x;
    if (i < 64 * 512) w1bf[i] = f2bf(W1[i]);
    if (i < 64 * 64)  w2bf[i] = f2bf(W2[i]);
}

// ---------------------------------------------------------------- fused MFMA MLP
// h = relu(x@W1^T + b1) @ W2^T + b2, bf16 out. Block = 256 thr = 4 waves,
// wave owns 64 rows. W1/W2 bf16 in LDS with XOR swizzle (T2); A-frags built
// from fp32 x loads converted in-register. Layer-2 via per-wave LDS staging
// (reuses W1's LDS after barrier).
__global__ __launch_bounds__(256, 2) void mlp_mfma_kernel(
    const float* __restrict__ x, const ushort* __restrict__ w1bf, const float* __restrict__ b1,
    const ushort* __restrict__ w2bf, const float* __restrict__ b2, ushort* __restrict__ h, int n)
{
    __shared__ ushort w1s[64 * 512];   // 64KB, swizzled: byte ^= ((row&7)<<4), row = byte>>10
    __shared__ ushort w2s[64 * 64];    // 8KB,  swizzled: row = byte>>7
    __shared__ float  b1s[64], b2s[64];

    int t = threadIdx.x;
    // stage W1 (4096 x 16B chunks, 16/thread)
    #pragma unroll
    for (int i = 0; i < 16; ++i) {
        int chunk = i * 256 + t;
        int byte = chunk * 16;
        int row = byte >> 10;
        int dst = byte ^ ((row & 7) << 4);
        *reinterpret_cast<uint4*>((char*)w1s + dst) = reinterpret_cast<const uint4*>(w1bf)[chunk];
    }
    // stage W2 (512 x 16B chunks, 2/thread)
    #pragma unroll
    for (int i = 0; i < 2; ++i) {
        int chunk = i * 256 + t;
        int byte = chunk * 16;
        int row = byte >> 7;
        int dst = byte ^ ((row & 7) << 4);
        *reinterpret_cast<uint4*>((char*)w2s + dst) = reinterpret_cast<const uint4*>(w2bf)[chunk];
    }
    if (t < 64) { b1s[t] = b1[t]; b2s[t] = b2[t]; }
    __syncthreads();

    int wid = t >> 6;
    int l   = t & 63;
    int lr  = l & 15;     // row (A) / col (B,D) within 16
    int lk  = l >> 4;     // k-group
    int rowbase = blockIdx.x * 256 + wid * 64;

    // ---------------- layer 1: C1[64x64] = x[64x512] @ W1^T ----------------
    f32x4 acc[4][4] = {};
    for (int kk = 0; kk < 16; ++kk) {
        int k0 = kk * 32 + lk * 8;
        bf16x8 a[4];
        #pragma unroll
        for (int fr = 0; fr < 4; ++fr) {
            int row = rowbase + fr * 16 + lr;
            row = (row < n) ? row : (n - 1);
            const float* p = x + (size_t)row * F_IN + k0;
            float4 u0 = *reinterpret_cast<const float4*>(p);
            float4 u1 = *reinterpret_cast<const float4*>(p + 4);
            bf16x8 af;
            af[0] = (short)f2bf(u0.x); af[1] = (short)f2bf(u0.y);
            af[2] = (short)f2bf(u0.z); af[3] = (short)f2bf(u0.w);
            af[4] = (short)f2bf(u1.x); af[5] = (short)f2bf(u1.y);
            af[6] = (short)f2bf(u1.z); af[7] = (short)f2bf(u1.w);
            a[fr] = af;
        }
        bf16x8 b[4];
        #pragma unroll
        for (int fc = 0; fc < 4; ++fc) {
            int nn = fc * 16 + lr;
            int byte = nn * 1024 + k0 * 2;
            b[fc] = *reinterpret_cast<const bf16x8*>((char*)w1s + (byte ^ ((nn & 7) << 4)));
        }
        #pragma unroll
        for (int fr = 0; fr < 4; ++fr)
            #pragma unroll
            for (int fc = 0; fc < 4; ++fc)
                acc[fr][fc] = __builtin_amdgcn_mfma_f32_16x16x32_bf16(a[fr], b[fc], acc[fr][fc], 0, 0, 0);
    }

    // ---------------- bias + relu, stage C1 to per-wave LDS (reuse w1s) ----
    __syncthreads();   // all waves done reading w1s
    ushort* h1w = w1s + wid * 4096;   // 64x64 bf16 per wave, swizzled (row = byte>>7)
    #pragma unroll
    for (int fr = 0; fr < 4; ++fr) {
        #pragma unroll
        for (int fc = 0; fc < 4; ++fc) {
            #pragma unroll
            for (int reg = 0; reg < 4; ++reg) {
                float v = acc[fr][fc][reg] + b1s[fc * 16 + lr];
                v = fmaxf(v, 0.f);
                int row = fr * 16 + lk * 4 + reg;   // local row 0..63
                int col = fc * 16 + lr;
                int byte = row * 128 + col * 2;
                *reinterpret_cast<ushort*>((char*)h1w + (byte ^ ((row & 7) << 4))) = f2bf(v);
            }
        }
    }

    // ---------------- layer 2: C2[64x64] = C1 @ W2^T ----------------------
    f32x4 acc2[4][4] = {};
    #pragma unroll
    for (int kk = 0; kk < 2; ++kk) {
        int k0 = kk * 32 + lk * 8;
        bf16x8 a2[4], bb[4];
        #pragma unroll
        for (int fr = 0; fr < 4; ++fr) {
            int row = fr * 16 + lr;
            int byte = row * 128 + k0 * 2;
            a2[fr] = *reinterpret_cast<const bf16x8*>((char*)h1w + (byte ^ ((row & 7) << 4)));
        }
        #pragma unroll
        for (int fc = 0; fc < 4; ++fc) {
            int nn = fc * 16 + lr;
            int byte = nn * 128 + k0 * 2;
            bb[fc] = *reinterpret_cast<const bf16x8*>((char*)w2s + (byte ^ ((nn & 7) << 4)));
        }
        #pragma unroll
        for (int fr = 0; fr < 4; ++fr)
            #pragma unroll
            for (int fc = 0; fc < 4; ++fc)
                acc2[fr][fc] = __builtin_amdgcn_mfma_f32_16x16x32_bf16(a2[fr], bb[fc], acc2[fr][fc], 0, 0, 0);
    }

    // ---------------- epilogue: + b2, bf16 store ---------------------------
    #pragma unroll
    for (int fr = 0; fr < 4; ++fr) {
        #pragma unroll
        for (int fc = 0; fc < 4; ++fc) {
            #pragma unroll
            for (int reg = 0; reg < 4; ++reg) {
                int row = rowbase + fr * 16 + lk * 4 + reg;
                int col = fc * 16 + lr;
                if (row < n)
                    h[(size_t)row * C_DIM + col] = f2bf(acc2[fr][fc][reg] + b2s[col]);
            }
        }
    }
}

// ---------------------------------------------------------------- one APPNP step: wave per node, lane = channel (bf16 z)
__global__ __launch_bounds__(256) void appnp_kernel(
    const int* __restrict__ row_start, const int* __restrict__ csr_src,
    const float* __restrict__ csr_norm, const float* __restrict__ selfw,
    const ushort* __restrict__ zin, const ushort* __restrict__ h,
    ushort* __restrict__ zout, int n)
{
    int idx = blockIdx.x * blockDim.x + threadIdx.x;
    int wid = idx >> 6;
    int lane = idx & 63;
    if (wid >= n) return;
    int beg = row_start[wid];
    int end = row_start[wid + 1];
    float a0 = 0.f, a1 = 0.f, a2 = 0.f, a3 = 0.f;
    int e = beg;
    for (; e + 3 < end; e += 4) {
        int s0 = csr_src[e], s1 = csr_src[e + 1], s2 = csr_src[e + 2], s3 = csr_src[e + 3];
        float w0 = csr_norm[e], w1 = csr_norm[e + 1], w2 = csr_norm[e + 2], w3 = csr_norm[e + 3];
        a0 = fmaf(w0, bf2f(zin[(size_t)s0 * 64 + lane]), a0);
        a1 = fmaf(w1, bf2f(zin[(size_t)s1 * 64 + lane]), a1);
        a2 = fmaf(w2, bf2f(zin[(size_t)s2 * 64 + lane]), a2);
        a3 = fmaf(w3, bf2f(zin[(size_t)s3 * 64 + lane]), a3);
    }
    for (; e < end; ++e) {
        int s = csr_src[e];
        a0 = fmaf(csr_norm[e], bf2f(zin[(size_t)s * 64 + lane]), a0);
    }
    float acc = (a0 + a1) + (a2 + a3);
    float zi = bf2f(zin[(size_t)wid * 64 + lane]);
    float agg = acc + selfw[wid] * zi;
    float res = (1.0f - ALPHA) * agg + ALPHA * bf2f(h[(size_t)wid * 64 + lane]);
    zout[(size_t)wid * 64 + lane] = f2bf(res);
}

// ---------------------------------------------------------------- log_softmax over C=64 (wave per node)
__global__ __launch_bounds__(256) void logsoftmax_kernel(const ushort* __restrict__ z,
                                                         float* __restrict__ out, int n) {
    int idx = blockIdx.x * blockDim.x + threadIdx.x;
    int wid = idx >> 6;
    int lane = idx & 63;
    if (wid >= n) return;
    float v = bf2f(z[(size_t)wid * 64 + lane]);
    float m = v;
    #pragma unroll
    for (int off = 32; off > 0; off >>= 1) m = fmaxf(m, __shfl_xor(m, off));
    float ex = expf(v - m);
    float s = ex;
    #pragma unroll
    for (int off = 32; off > 0; off >>= 1) s += __shfl_xor(s, off);
    out[(size_t)wid * 64 + lane] = v - m - logf(s);
}

// ---------------------------------------------------------------- launch
extern "C" void kernel_launch(void* const* d_in, const int* in_sizes, int n_in,
                              void* d_out, int out_size, void* d_ws, size_t ws_size,
                              hipStream_t stream) {
    const float* x  = (const float*)d_in[0];
    const float* W1 = (const float*)d_in[1];
    const float* b1 = (const float*)d_in[2];
    const float* W2 = (const float*)d_in[3];
    const float* b2 = (const float*)d_in[4];
    const int*   ei = (const int*)d_in[5];
    const int* src = ei;
    const int* dst = ei + N_EDGES;
    float* out = (float*)d_out;

    char* ws = (char*)d_ws;
    size_t off = 0;
    auto alloc = [&](size_t bytes) -> void* {
        void* p = ws + off;
        off += (bytes + 255) & ~(size_t)255;
        return p;
    };
    int*    deg       = (int*)   alloc((size_t)N_NODES * 4);
    int*    cursor    = (int*)   alloc((size_t)N_NODES * 4);
    int*    row_start = (int*)   alloc((size_t)(N_NODES + 1) * 4);
    float*  dinv      = (float*) alloc((size_t)N_NODES * 4);
    float*  selfw     = (float*) alloc((size_t)N_NODES * 4);
    int*    csr_src   = (int*)   alloc((size_t)N_EDGES * 4);
    float*  csr_norm  = (float*) alloc((size_t)N_EDGES * 4);
    ushort* h         = (ushort*)alloc((size_t)N_NODES * C_DIM * 2);
    ushort* za        = (ushort*)alloc((size_t)N_NODES * C_DIM * 2);
    ushort* zb        = (ushort*)alloc((size_t)N_NODES * C_DIM * 2);
    ushort* w1bf      = (ushort*)alloc((size_t)H_DIM * F_IN * 2);
    ushort* w2bf      = (ushort*)alloc((size_t)C_DIM * H_DIM * 2);

    zero_kernel<<<(N_NODES + 255) / 256, 256, 0, stream>>>(deg, cursor, N_NODES);
    deg_kernel<<<(N_EDGES + 255) / 256, 256, 0, stream>>>(dst, deg, N_EDGES);
    dinv_kernel<<<(N_NODES + 255) / 256, 256, 0, stream>>>(deg, dinv, selfw, N_NODES);
    scan_kernel<<<1, 1024, 0, stream>>>(deg, row_start, N_NODES);
    scatter_kernel<<<(N_EDGES + 255) / 256, 256, 0, stream>>>(src, dst, row_start, cursor,
                                                              dinv, csr_src, csr_norm, N_EDGES);
    cvt_w_kernel<<<(H_DIM * F_IN + 255) / 256, 256, 0, stream>>>(W1, W2, w1bf, w2bf);
    mlp_mfma_kernel<<<(N_NODES + 255) / 256, 256, 0, stream>>>(x, w1bf, b1, w2bf, b2, h, N_NODES);

    const ushort* zin = h;
    ushort* zout = za;
    for (int k = 0; k < K_STEPS; ++k) {
        appnp_kernel<<<(N_NODES * 64 + 255) / 256, 256, 0, stream>>>(
            row_start, csr_src, csr_norm, selfw, zin, h, zout, N_NODES);
        zin = zout;
        zout = (zout == za) ? zb : za;
    }
    logsoftmax_kernel<<<(N_NODES * 64 + 255) / 256, 256, 0, stream>>>(zin, out, N_NODES);
}